// Round 2
// baseline (1207.437 us; speedup 1.0000x reference)
//
#include <hip/hip_runtime.h>
#include <cstdint>

#define DEV __device__ __forceinline__

typedef __attribute__((ext_vector_type(8))) short bf16x8;
typedef __attribute__((ext_vector_type(4))) float f32x4;
typedef unsigned short u16;
typedef unsigned int   u32;

// ---------- bf16 helpers (manual RNE) ----------
DEV u16 f2bf(float f) {
  u32 u = __float_as_uint(f);
  u = (u + 0x7FFFu + ((u >> 16) & 1u)) >> 16;
  return (u16)u;
}
DEV float bf2f(u16 s) { return __uint_as_float(((u32)s) << 16); }

DEV float gelu_f(float x) { return 0.5f * x * (1.f + erff(x * 0.70710678118654752f)); }

// ---------- async global->LDS (16B per lane) ----------
DEV void gload_lds16(const void* g, void* l) {
  typedef __attribute__((address_space(1))) const unsigned int GU;
  typedef __attribute__((address_space(3))) unsigned int LU;
  __builtin_amdgcn_global_load_lds((GU*)(uintptr_t)g, (LU*)(u32)(uintptr_t)l, 16, 0, 0);
}

// =====================================================================
// GEMM: C[M,N] = A[M,K] @ Bt[N,K]^T, bf16 in, f32 accum.
// 128x128 tile, BK=64, 4 waves (2x2), 16x16x32 MFMA, global_load_lds staging.
// MODE 0: out bf16, +bias                       (QKV)
// MODE 1: out f32 * scale, causal tile skip     (scores; grid x=nt,y=mt)
// MODE 2: out bf16, Keff=(mt+1)*128             (PV, block-causal)
// MODE 3: out bf16, +bias, gelu                 (FFN1)
// MODE 4: out f32, +bias, +resid bf16           (FFN2 -> d_out)
// =====================================================================
template<int MODE>
__global__ __launch_bounds__(256, 2)
void gemm_bt(const u16* __restrict__ A, int lda,
             const u16* __restrict__ Bt, int ldb,
             void* __restrict__ Cv, int ldc,
             const float* __restrict__ bias,
             const u16* __restrict__ resid, int ldr,
             int K, float scale)
{
  const int nt = blockIdx.x, mt = blockIdx.y;
  if (MODE == 1 && nt > mt) return;            // causal: skip upper-triangle tiles
  const int Keff = (MODE == 2) ? (mt + 1) * 128 : K;

  __shared__ u16 As[128 * 64];
  __shared__ u16 Bs[128 * 64];

  const int tid  = threadIdx.x;
  const int lane = tid & 63;
  const int wv   = tid >> 6;
  const int wr   = wv >> 1, wc = wv & 1;       // 2x2 wave grid, each wave 64x64
  const int lrow = lane & 15;
  const int kgrp = lane >> 4;

  const int m0 = mt * 128, n0 = nt * 128;

  // staging: 256 threads x 16B -> 32 rows x 64 bf16 per issue
  const int srow = tid >> 3;
  const int scol = (tid & 7) * 8;
  const u16* Ag = A + (long)(m0 + srow) * lda + scol;
  const u16* Bg = Bt + (long)(n0 + srow) * ldb + scol;
  char* AsW = (char*)As + wv * 1024;           // wave-uniform LDS base
  char* BsW = (char*)Bs + wv * 1024;

  f32x4 acc[4][4];
#pragma unroll
  for (int mi = 0; mi < 4; ++mi)
#pragma unroll
    for (int ni = 0; ni < 4; ++ni)
#pragma unroll
      for (int e = 0; e < 4; ++e) acc[mi][ni][e] = 0.f;

  for (int k0 = 0; k0 < Keff; k0 += 64) {
#pragma unroll
    for (int i = 0; i < 4; ++i) {
      gload_lds16(Ag + k0 + (long)i * 32 * lda, AsW + i * 4096);
      gload_lds16(Bg + k0 + (long)i * 32 * ldb, BsW + i * 4096);
    }
    __syncthreads();
#pragma unroll
    for (int kk = 0; kk < 2; ++kk) {
      const int kof = kk * 32 + kgrp * 8;
      bf16x8 af[4], bfr[4];
#pragma unroll
      for (int mi = 0; mi < 4; ++mi)
        af[mi] = *(const bf16x8*)&As[(wr * 64 + mi * 16 + lrow) * 64 + kof];
#pragma unroll
      for (int ni = 0; ni < 4; ++ni)
        bfr[ni] = *(const bf16x8*)&Bs[(wc * 64 + ni * 16 + lrow) * 64 + kof];
#pragma unroll
      for (int mi = 0; mi < 4; ++mi)
#pragma unroll
        for (int ni = 0; ni < 4; ++ni)
          acc[mi][ni] = __builtin_amdgcn_mfma_f32_16x16x32_bf16(af[mi], bfr[ni], acc[mi][ni], 0, 0, 0);
    }
    __syncthreads();
  }

  // epilogue: C/D layout col=lane&15, row=(lane>>4)*4+e  [m89-verified]
#pragma unroll
  for (int mi = 0; mi < 4; ++mi) {
#pragma unroll
    for (int ni = 0; ni < 4; ++ni) {
      const int gc = n0 + wc * 64 + ni * 16 + lrow;
      const float bv = (MODE == 0 || MODE == 3 || MODE == 4) ? bias[gc] : 0.f;
#pragma unroll
      for (int e = 0; e < 4; ++e) {
        const int gr = m0 + wr * 64 + mi * 16 + kgrp * 4 + e;
        const float v = acc[mi][ni][e];
        const long cidx = (long)gr * ldc + gc;
        if (MODE == 0) {
          ((u16*)Cv)[cidx] = f2bf(v + bv);
        } else if (MODE == 1) {
          ((float*)Cv)[cidx] = v * scale;
        } else if (MODE == 2) {
          ((u16*)Cv)[cidx] = f2bf(v);
        } else if (MODE == 3) {
          ((u16*)Cv)[cidx] = f2bf(gelu_f(v + bv));
        } else {
          ((float*)Cv)[cidx] = v + bv + bf2f(resid[(long)gr * ldr + gc]);
        }
      }
    }
  }
}

// ---------- transpose (+convert) to bf16 [C][R]; INBF: 0=f32 in, 1=bf16 in ----------
template<int INBF>
__global__ __launch_bounds__(256)
void transpose_bf16(const void* __restrict__ inv, u16* __restrict__ out,
                    int R, int C, long ibst, long obst)
{
  __shared__ float t[32][33];
  const int bz = blockIdx.z;
  const int c0 = blockIdx.x * 32, r0 = blockIdx.y * 32;
  const int tx = threadIdx.x & 31, ty = threadIdx.x >> 5;
#pragma unroll
  for (int i = 0; i < 32; i += 8) {
    const long idx = (long)bz * ibst + (long)(r0 + ty + i) * C + (c0 + tx);
    t[ty + i][tx] = INBF ? bf2f(((const u16*)inv)[idx]) : ((const float*)inv)[idx];
  }
  __syncthreads();
#pragma unroll
  for (int i = 0; i < 32; i += 8)
    out[(long)bz * obst + (long)(c0 + ty + i) * R + (r0 + tx)] = f2bf(t[tx][ty + i]);
}

// ---------- f32 -> bf16 convert ----------
__global__ __launch_bounds__(256)
void cvt_f32_to_bf16(const float* __restrict__ in, u16* __restrict__ out, long n)
{
  const long idx = ((long)blockIdx.x * 256 + threadIdx.x) * 4;
  if (idx >= n) return;
  const float4 v = *(const float4*)(in + idx);
  ushort4 o;
  o.x = f2bf(v.x); o.y = f2bf(v.y); o.z = f2bf(v.z); o.w = f2bf(v.w);
  *(ushort4*)(out + idx) = o;
}

// ---------- causal row softmax, in-place f32 scores -> bf16 probs (one batch) ----------
__global__ __launch_bounds__(256)
void softmax_causal(float* __restrict__ scores)
{
  const int i = blockIdx.x;               // row in [0,2048)
  float* row = scores + (long)i * 2048;
  const int t = threadIdx.x;
  const int lane = t & 63, wv = t >> 6;
  const int L = i + 1;
  float m = -1e30f;
#pragma unroll
  for (int u = 0; u < 8; ++u) { const int j = t + u * 256; if (j < L) m = fmaxf(m, row[j]); }
#pragma unroll
  for (int o = 1; o < 64; o <<= 1) m = fmaxf(m, __shfl_xor(m, o));
  __shared__ float rm[4], rsm[4];
  if (lane == 0) rm[wv] = m;
  __syncthreads();
  m = fmaxf(fmaxf(rm[0], rm[1]), fmaxf(rm[2], rm[3]));
  float pv[8];
  float s = 0.f;
#pragma unroll
  for (int u = 0; u < 8; ++u) {
    const int j = t + u * 256;
    const float e = (j < L) ? expf(row[j] - m) : 0.f;
    pv[u] = e; s += e;
  }
#pragma unroll
  for (int o = 1; o < 64; o <<= 1) s += __shfl_xor(s, o);
  if (lane == 0) rsm[wv] = s;
  __syncthreads();   // all f32 reads complete before bf16 overwrite begins
  s = rsm[0] + rsm[1] + rsm[2] + rsm[3];
  const float inv = 1.f / s;
  u16* prow = (u16*)row;                  // bf16 probs in-place, row stride 4096 elems
  const int Lpad = ((i >> 7) + 1) << 7;   // zero-fill to this q-tile's k-extent
#pragma unroll
  for (int u = 0; u < 8; ++u) {
    const int j = t + u * 256;
    if (j < Lpad) prow[j] = f2bf(pv[u] * inv);
  }
}

// ---------- LayerNorm rows of 1024; INBF/OUTBF select bf16 vs f32; in-place safe ----------
template<int INBF, int OUTBF>
__global__ __launch_bounds__(256)
void layernorm_k(const void* in, const float* gam, const float* bet, void* outv)
{
  const long row = blockIdx.x;
  const int t = threadIdx.x;
  const int lane = t & 63, wv = t >> 6;
  float v0, v1, v2, v3;
  if (INBF) {
    const ushort4 u = ((const ushort4*)in)[row * 256 + t];
    v0 = bf2f(u.x); v1 = bf2f(u.y); v2 = bf2f(u.z); v3 = bf2f(u.w);
  } else {
    const float4 v = ((const float4*)in)[row * 256 + t];
    v0 = v.x; v1 = v.y; v2 = v.z; v3 = v.w;
  }
  float s = v0 + v1 + v2 + v3;
  float q = v0 * v0 + v1 * v1 + v2 * v2 + v3 * v3;
#pragma unroll
  for (int o = 1; o < 64; o <<= 1) { s += __shfl_xor(s, o); q += __shfl_xor(q, o); }
  __shared__ float rs[4], rq[4];
  if (lane == 0) { rs[wv] = s; rq[wv] = q; }
  __syncthreads();
  s = rs[0] + rs[1] + rs[2] + rs[3];
  q = rq[0] + rq[1] + rq[2] + rq[3];
  const float mean = s * (1.f / 1024.f);
  const float var  = q * (1.f / 1024.f) - mean * mean;
  const float rstd = rsqrtf(var + 1e-5f);
  const float4 g4 = ((const float4*)gam)[t];
  const float4 b4 = ((const float4*)bet)[t];
  const float o0 = (v0 - mean) * rstd * g4.x + b4.x;
  const float o1 = (v1 - mean) * rstd * g4.y + b4.y;
  const float o2 = (v2 - mean) * rstd * g4.z + b4.z;
  const float o3 = (v3 - mean) * rstd * g4.w + b4.w;
  if (OUTBF) {
    ushort4 o; o.x = f2bf(o0); o.y = f2bf(o1); o.z = f2bf(o2); o.w = f2bf(o3);
    ((ushort4*)outv)[row * 256 + t] = o;
  } else {
    ((float4*)outv)[row * 256 + t] = make_float4(o0, o1, o2, o3);
  }
}

// =====================================================================
extern "C" void kernel_launch(void* const* d_in, const int* in_sizes, int n_in,
                              void* d_out, int out_size, void* d_ws, size_t ws_size,
                              hipStream_t stream)
{
  const float* x   = (const float*)d_in[0];
  const float* Wq  = (const float*)d_in[1];
  const float* bq  = (const float*)d_in[2];
  const float* Wk  = (const float*)d_in[3];
  const float* bk  = (const float*)d_in[4];
  const float* Wv  = (const float*)d_in[5];
  const float* bv  = (const float*)d_in[6];
  const float* W1  = (const float*)d_in[7];
  const float* b1  = (const float*)d_in[8];
  const float* W2  = (const float*)d_in[9];
  const float* b2  = (const float*)d_in[10];
  const float* g1  = (const float*)d_in[11];
  const float* be1 = (const float*)d_in[12];
  const float* g2  = (const float*)d_in[13];
  const float* be2 = (const float*)d_in[14];

  // workspace layout — 174,063,616 B total (166 MiB), stream-ordered reuse:
  //  [0      , 32M )  xb (x bf16)        -> vt (v^T bf16) after QKV
  //  [32M    , 96M )  q | k              -> h (FFN hidden chunk, 64 MiB) after scores
  //  [96M    , 128M)  v                  -> attn bf16 (PV out) -> ln1 (LN1 in-place)
  //  [128M   , 144M)  scores f32 / probs bf16, one batch (16 MiB)
  //  [144M   , ...)   bf16 [N][K] weights: Wq|Wk|Wv (6M), W1 (8M), W2 (8M)
  char* ws = (char*)d_ws;
  u16*   xb    = (u16*)(ws);
  u16*   vt    = xb;
  u16*   qbuf  = (u16*)(ws + 33554432);
  u16*   kbuf  = (u16*)(ws + 67108864);
  u16*   hbuf  = (u16*)(ws + 33554432);        // 64 MiB over q+k
  u16*   vbuf  = (u16*)(ws + 100663296);
  u16*   attn  = vbuf;                          // PV out bf16, LN1 in-place -> ln1
  u16*   ln1   = vbuf;
  float* sc    = (float*)(ws + 134217728);      // 16 MiB per-batch scores
  u16*   wqkvT = (u16*)(ws + 150994944);
  u16*   w1T   = (u16*)(ws + 157286400);
  u16*   w2T   = (u16*)(ws + 165675008);

  const dim3 B256(256);

  // 1. x -> bf16
  cvt_f32_to_bf16<<<dim3(16384), B256, 0, stream>>>(x, xb, 16777216L);

  // 2. weight transposes: f32 [K][N] -> bf16 [N][K]
  transpose_bf16<0><<<dim3(32, 32, 1),  B256, 0, stream>>>(Wq, wqkvT,           1024, 1024, 0, 0);
  transpose_bf16<0><<<dim3(32, 32, 1),  B256, 0, stream>>>(Wk, wqkvT + 1048576, 1024, 1024, 0, 0);
  transpose_bf16<0><<<dim3(32, 32, 1),  B256, 0, stream>>>(Wv, wqkvT + 2097152, 1024, 1024, 0, 0);
  transpose_bf16<0><<<dim3(128, 32, 1), B256, 0, stream>>>(W1, w1T, 1024, 4096, 0, 0);
  transpose_bf16<0><<<dim3(32, 128, 1), B256, 0, stream>>>(W2, w2T, 4096, 1024, 0, 0);

  // 3. QKV projections (M=16384, N=1024, K=1024)
  gemm_bt<0><<<dim3(8, 128), B256, 0, stream>>>(xb, 1024, wqkvT,           1024, qbuf, 1024, bq, nullptr, 0, 1024, 1.f);
  gemm_bt<0><<<dim3(8, 128), B256, 0, stream>>>(xb, 1024, wqkvT + 1048576, 1024, kbuf, 1024, bk, nullptr, 0, 1024, 1.f);
  gemm_bt<0><<<dim3(8, 128), B256, 0, stream>>>(xb, 1024, wqkvT + 2097152, 1024, vbuf, 1024, bv, nullptr, 0, 1024, 1.f);

  // 4. v -> v^T per batch (2048x1024 -> 1024x2048), overwrites xb (dead)
  transpose_bf16<1><<<dim3(32, 64, 8), B256, 0, stream>>>(vbuf, vt, 2048, 1024, 2097152, 2097152);

  // 5. attention, one batch at a time (stream-ordered reuse of sc)
  for (int b = 0; b < 8; ++b) {
    const u16* qb = qbuf + (long)b * 2097152;
    const u16* kb = kbuf + (long)b * 2097152;
    const u16* vtb = vt + (long)b * 2097152;
    u16* ab = attn + (long)b * 2097152;
    // scores = q @ k^T / 32 (f32, lower-triangle tiles only)
    gemm_bt<1><<<dim3(16, 16), B256, 0, stream>>>(qb, 1024, kb, 1024, sc, 2048, nullptr, nullptr, 0, 1024, 0.03125f);
    // row softmax in-place -> bf16 probs (row stride 4096 bf16)
    softmax_causal<<<dim3(2048), B256, 0, stream>>>(sc);
    // attn_out = probs @ v^T^T (block-causal K-extent), bf16 out
    gemm_bt<2><<<dim3(8, 16), B256, 0, stream>>>((const u16*)sc, 4096, vtb, 2048, ab, 1024, nullptr, nullptr, 0, 0, 1.f);
  }

  // 6. LN1 in-place on attn -> ln1 (bf16)
  layernorm_k<1, 1><<<dim3(16384), B256, 0, stream>>>(attn, g1, be1, ln1);

  // 7. FFN in 2 chunks of M=8192, h reuses dead q/k (64 MiB)
  for (int c = 0; c < 2; ++c) {
    const u16* lc = ln1 + (long)c * 8192 * 1024;
    float* oc = (float*)d_out + (long)c * 8192 * 1024;
    // h = gelu(ln1 @ W1 + b1) bf16 (8192 x 4096)
    gemm_bt<3><<<dim3(32, 64), B256, 0, stream>>>(lc, 1024, w1T, 1024, hbuf, 4096, b1, nullptr, 0, 1024, 1.f);
    // out = h @ W2 + b2 + ln1 -> f32 directly into d_out
    gemm_bt<4><<<dim3(8, 64), B256, 0, stream>>>(hbuf, 4096, w2T, 4096, oc, 1024, b2, lc, 1024, 4096, 1.f);
  }

  // 8. LN2 in-place on d_out (f32)
  layernorm_k<0, 0><<<dim3(16384), B256, 0, stream>>>(d_out, g2, be2, d_out);
}

// Round 3
// 885.671 us; speedup vs baseline: 1.3633x; 1.3633x over previous
//
#include <hip/hip_runtime.h>
#include <cstdint>

#define DEV __device__ __forceinline__

typedef __attribute__((ext_vector_type(8))) short bf16x8;
typedef __attribute__((ext_vector_type(4))) float f32x4;
typedef unsigned short u16;
typedef unsigned int   u32;

// ---------- bf16 helpers (manual RNE) ----------
DEV u16 f2bf(float f) {
  u32 u = __float_as_uint(f);
  u = (u + 0x7FFFu + ((u >> 16) & 1u)) >> 16;
  return (u16)u;
}
DEV float bf2f(u16 s) { return __uint_as_float(((u32)s) << 16); }

DEV float gelu_f(float x) { return 0.5f * x * (1.f + erff(x * 0.70710678118654752f)); }

// ---------- async global->LDS (16B per lane) ----------
DEV void gload_lds16(const void* g, void* l) {
  typedef __attribute__((address_space(1))) const unsigned int GU;
  typedef __attribute__((address_space(3))) unsigned int LU;
  __builtin_amdgcn_global_load_lds((GU*)(uintptr_t)g, (LU*)(u32)(uintptr_t)l, 16, 0, 0);
}

// packed causal score layout: per batch, 136 lower-triangle 128x128 tiles,
// tile (mt,nt) nt<=mt at (mt*(mt+1)/2 + nt)*16384, row-major inside.
#define BATCH_SC 2228224L   // u16 elements per batch (136*16384)

// =====================================================================
// gemm256: C[M,N] = A[M,K] @ Bt[N,K]^T, bf16 in, f32 accum.
// 256x256 tile, BK=64, 8 waves (2Mx4N), 512 thr, 8-phase counted-vmcnt
// pipeline (T3+T4), st_16x32 LDS XOR swizzle (T2), setprio (T5),
// XCD-bijective block swizzle (T1). LDS 128 KiB, 1 block/CU.
// MODE 0: QKV fused   -> bf16, +bias (bq/bk/bv routed by gc>>10)
// MODE 3: FFN1 half   -> bf16, +bias, gelu
// MODE 4: FFN2 pass 0 -> f32 raw partial
// MODE 5: FFN2 pass 1 -> f32 += partial + bias + resid(bf16)
// =====================================================================
template<int MODE>
__global__ __launch_bounds__(512, 2)
void gemm256(const u16* __restrict__ A, int lda,
             const u16* __restrict__ Bt, int ldb,
             void* __restrict__ Cv, int ldc,
             const float* __restrict__ bias,
             const float* __restrict__ bias2,
             const float* __restrict__ bias3,
             const u16* __restrict__ resid,
             int K, int NMT)
{
  __shared__ char smem[131072];  // 2 slots x (A 32K + B 32K)
  const int tid  = threadIdx.x;
  const int lane = tid & 63;
  const int wv   = tid >> 6;
  const int wm   = wv >> 2, wn = wv & 3;   // 2x4 wave grid; wave out 128x64
  const int lrow = lane & 15;
  const int kgrp = lane >> 4;

  // T1: bijective XCD swizzle (m204)
  const int nwg = gridDim.x;
  const int q0 = nwg >> 3, r = nwg & 7, xc = blockIdx.x & 7, pos = blockIdx.x >> 3;
  const int s = (xc < r ? xc * (q0 + 1) : r * (q0 + 1) + (xc - r) * q0) + pos;
  const int mt = s % NMT, nt = s / NMT;
  const int m0 = mt * 256, n0 = nt * 256;

  // stage one half-tile (128 rows x 64 bf16) = 2 x global_load_lds per thread.
  // T2 both-sides: linear LDS dest o, inverse-swizzled global source l.
  auto stageA = [&](int ktile, int dslot, int h) {
    int k0 = ktile << 6; const int kmax = K - 64; if (k0 > kmax) k0 = kmax;
#pragma unroll
    for (int j = 0; j < 2; ++j) {
      const int o = j * 8192 + tid * 16;
      const int l = o ^ (((o >> 9) & 1) << 5);
      gload_lds16(A + (long)(m0 + h * 128 + (l >> 7)) * lda + k0 + ((l & 127) >> 1),
                  smem + dslot * 65536 + h * 16384 + o);
    }
  };
  auto stageB = [&](int ktile, int dslot, int h) {
    int k0 = ktile << 6; const int kmax = K - 64; if (k0 > kmax) k0 = kmax;
#pragma unroll
    for (int j = 0; j < 2; ++j) {
      const int o = j * 8192 + tid * 16;
      const int l = o ^ (((o >> 9) & 1) << 5);
      gload_lds16(Bt + (long)(n0 + h * 128 + (l >> 7)) * ldb + k0 + ((l & 127) >> 1),
                  smem + dslot * 65536 + 32768 + h * 16384 + o);
    }
  };
  // swizzled fragment read (16B, ds_read_b128)
  auto rdfrag = [&](int bofs, int row, int ks) -> bf16x8 {
    int p = row * 128 + ks * 64 + kgrp * 16;
    p ^= ((p >> 9) & 1) << 5;
    return *(const bf16x8*)(smem + bofs + p);
  };

  f32x4 acc[8][4];
#pragma unroll
  for (int mi = 0; mi < 8; ++mi)
#pragma unroll
    for (int ni = 0; ni < 4; ++ni)
#pragma unroll
      for (int e = 0; e < 4; ++e) acc[mi][ni][e] = 0.f;

  // prologue: slot0 <- K-tile 0 (all), slot1 <- B of K-tile 1
  stageA(0, 0, 0); stageA(0, 0, 1); stageB(0, 0, 0); stageB(0, 0, 1);
  stageB(1, 1, 0); stageB(1, 1, 1);
  asm volatile("s_waitcnt vmcnt(4)" ::: "memory");  // K-tile 0 resident
  __builtin_amdgcn_s_barrier();

  const int NI = K >> 7;   // K/128 iterations, 2 K-tiles each (K%128==0)
  bf16x8 bfrag[4][2], afrag[2][2];
  for (int i = 0; i < NI; ++i) {
    const int kp = 2 * i;
#pragma unroll
    for (int d = 0; d < 2; ++d) {
#pragma unroll
      for (int mq = 0; mq < 4; ++mq) {
        const int ph = d * 4 + mq;
        if (mq == 0) {
#pragma unroll
          for (int ni = 0; ni < 4; ++ni)
#pragma unroll
            for (int ks = 0; ks < 2; ++ks)
              bfrag[ni][ks] = rdfrag(d * 65536 + 32768, wn * 64 + ni * 16 + lrow, ks);
        }
#pragma unroll
        for (int mi2 = 0; mi2 < 2; ++mi2)
#pragma unroll
          for (int ks = 0; ks < 2; ++ks)
            afrag[mi2][ks] = rdfrag(d * 65536, wm * 128 + (2 * mq + mi2) * 16 + lrow, ks);
        // prefetch issue map (race-free: dest rows' last ds_read is
        // barrier-separated; guarded by vmcnt(4) at ph3/ph7)
        switch (ph) {
          case 0: stageA(kp + 1, 1, 0); break;
          case 1: stageA(kp + 1, 1, 1); break;
          case 2: stageB(kp + 2, 0, 0); break;
          case 3: stageB(kp + 2, 0, 1); break;
          case 4: stageA(kp + 2, 0, 0); break;
          case 5: stageA(kp + 2, 0, 1); break;
          case 6: stageB(kp + 3, 1, 0); break;
          case 7: stageB(kp + 3, 1, 1); break;
        }
        __builtin_amdgcn_s_barrier();
        asm volatile("s_waitcnt lgkmcnt(0)" ::: "memory");
        __builtin_amdgcn_sched_barrier(0);
        __builtin_amdgcn_s_setprio(1);
#pragma unroll
        for (int mi2 = 0; mi2 < 2; ++mi2)
#pragma unroll
          for (int ni = 0; ni < 4; ++ni)
#pragma unroll
            for (int ks = 0; ks < 2; ++ks)
              acc[2 * mq + mi2][ni] = __builtin_amdgcn_mfma_f32_16x16x32_bf16(
                  afrag[mi2][ks], bfrag[ni][ks], acc[2 * mq + mi2][ni], 0, 0, 0);
        __builtin_amdgcn_s_setprio(0);
        __builtin_amdgcn_sched_barrier(0);
        if (mq == 3) asm volatile("s_waitcnt vmcnt(4)" ::: "memory");
        __builtin_amdgcn_s_barrier();
      }
    }
  }

  // epilogue: C/D layout col=lane&15, row=(lane>>4)*4+e [m89]
#pragma unroll
  for (int mi = 0; mi < 8; ++mi) {
#pragma unroll
    for (int ni = 0; ni < 4; ++ni) {
      const int gc = n0 + wn * 64 + ni * 16 + lrow;
#pragma unroll
      for (int e = 0; e < 4; ++e) {
        const int gr = m0 + wm * 128 + mi * 16 + kgrp * 4 + e;
        const float v = acc[mi][ni][e];
        if (MODE == 0) {
          const float bval = gc < 1024 ? bias[gc] : (gc < 2048 ? bias2[gc & 1023] : bias3[gc & 1023]);
          ((u16*)Cv)[(long)(gc >> 10) * 16777216 + (long)gr * 1024 + (gc & 1023)] = f2bf(v + bval);
        } else if (MODE == 3) {
          ((u16*)Cv)[(long)gr * ldc + gc] = f2bf(gelu_f(v + bias[gc]));
        } else if (MODE == 4) {
          ((float*)Cv)[(long)gr * ldc + gc] = v;
        } else {
          float* o = (float*)Cv + (long)gr * ldc + gc;
          *o = *o + v + bias[gc] + bf2f(resid[(long)gr * 1024 + gc]);
        }
      }
    }
  }
}

// =====================================================================
// gemm_bt 128x128 (proven R2 structure) for attention GEMMs, grid.z=batch
// MODE 1: scores = q@k^T*scale -> packed causal bf16 tiles
// MODE 2: attn = probs(packed)@vt^T -> f32 (d_out), Keff=(mt+1)*128
// =====================================================================
template<int MODE>
__global__ __launch_bounds__(256, 2)
void gemm_bt(const u16* __restrict__ A, int lda, long abst,
             const u16* __restrict__ Bt, int ldb, long bbst,
             void* __restrict__ Cv, int ldc, long cbst,
             int K, float scale)
{
  const int nt = blockIdx.x, mt = blockIdx.y, bz = blockIdx.z;
  if (MODE == 1 && nt > mt) return;
  const int Keff = (MODE == 2) ? (mt + 1) * 128 : K;

  __shared__ u16 As[128 * 64];
  __shared__ u16 Bs[128 * 64];

  const int tid  = threadIdx.x;
  const int lane = tid & 63;
  const int wv   = tid >> 6;
  const int wr   = wv >> 1, wc = wv & 1;
  const int lrow = lane & 15;
  const int kgrp = lane >> 4;
  const int m0 = mt * 128, n0 = nt * 128;

  const int srow = tid >> 3;
  const int scol = (tid & 7) * 8;
  const u16* Ag;
  if (MODE == 2) {  // packed probs: chunk (k0>>7) at tri-offset, row stride 128
    Ag = A + bz * BATCH_SC + (long)(mt * (mt + 1) / 2) * 16384 + srow * 128 + scol;
  } else {
    Ag = A + (long)bz * abst + (long)(m0 + srow) * lda + scol;
  }
  const u16* Bg = Bt + (long)bz * bbst + (long)(n0 + srow) * ldb + scol;
  char* AsW = (char*)As + wv * 1024;
  char* BsW = (char*)Bs + wv * 1024;

  f32x4 acc[4][4];
#pragma unroll
  for (int mi = 0; mi < 4; ++mi)
#pragma unroll
    for (int ni = 0; ni < 4; ++ni)
#pragma unroll
      for (int e = 0; e < 4; ++e) acc[mi][ni][e] = 0.f;

  for (int k0 = 0; k0 < Keff; k0 += 64) {
#pragma unroll
    for (int i = 0; i < 4; ++i) {
      if (MODE == 2)
        gload_lds16(Ag + (long)(k0 >> 7) * 16384 + (k0 & 127) + i * 32 * 128, AsW + i * 4096);
      else
        gload_lds16(Ag + k0 + (long)i * 32 * lda, AsW + i * 4096);
      gload_lds16(Bg + k0 + (long)i * 32 * ldb, BsW + i * 4096);
    }
    __syncthreads();
#pragma unroll
    for (int kk = 0; kk < 2; ++kk) {
      const int kof = kk * 32 + kgrp * 8;
      bf16x8 af[4], bfr[4];
#pragma unroll
      for (int mi = 0; mi < 4; ++mi)
        af[mi] = *(const bf16x8*)&As[(wr * 64 + mi * 16 + lrow) * 64 + kof];
#pragma unroll
      for (int ni = 0; ni < 4; ++ni)
        bfr[ni] = *(const bf16x8*)&Bs[(wc * 64 + ni * 16 + lrow) * 64 + kof];
#pragma unroll
      for (int mi = 0; mi < 4; ++mi)
#pragma unroll
        for (int ni = 0; ni < 4; ++ni)
          acc[mi][ni] = __builtin_amdgcn_mfma_f32_16x16x32_bf16(af[mi], bfr[ni], acc[mi][ni], 0, 0, 0);
    }
    __syncthreads();
  }

#pragma unroll
  for (int mi = 0; mi < 4; ++mi) {
#pragma unroll
    for (int ni = 0; ni < 4; ++ni) {
#pragma unroll
      for (int e = 0; e < 4; ++e) {
        const int rr = wr * 64 + mi * 16 + kgrp * 4 + e;   // row in tile
        const int cc = wc * 64 + ni * 16 + lrow;           // col in tile
        const float v = acc[mi][ni][e];
        if (MODE == 1) {
          ((u16*)Cv)[bz * BATCH_SC + (long)(mt * (mt + 1) / 2 + nt) * 16384 + rr * 128 + cc]
              = f2bf(v * scale);
        } else {
          ((float*)Cv)[(long)bz * cbst + (long)(m0 + rr) * ldc + n0 + cc] = v;
        }
      }
    }
  }
}

// ---------- transpose (+convert) to bf16 [C][R]; INBF: 0=f32, 1=bf16 ----------
template<int INBF>
__global__ __launch_bounds__(256)
void transpose_bf16(const void* __restrict__ inv, u16* __restrict__ out,
                    int R, int C, long ibst, long obst)
{
  __shared__ float t[32][33];
  const int bz = blockIdx.z;
  const int c0 = blockIdx.x * 32, r0 = blockIdx.y * 32;
  const int tx = threadIdx.x & 31, ty = threadIdx.x >> 5;
#pragma unroll
  for (int i = 0; i < 32; i += 8) {
    const long idx = (long)bz * ibst + (long)(r0 + ty + i) * C + (c0 + tx);
    t[ty + i][tx] = INBF ? bf2f(((const u16*)inv)[idx]) : ((const float*)inv)[idx];
  }
  __syncthreads();
#pragma unroll
  for (int i = 0; i < 32; i += 8)
    out[(long)bz * obst + (long)(c0 + ty + i) * R + (r0 + tx)] = f2bf(t[tx][ty + i]);
}

// ---------- f32 -> bf16 convert ----------
__global__ __launch_bounds__(256)
void cvt_f32_to_bf16(const float* __restrict__ in, u16* __restrict__ out, long n)
{
  const long idx = ((long)blockIdx.x * 256 + threadIdx.x) * 4;
  if (idx >= n) return;
  const float4 v = *(const float4*)(in + idx);
  ushort4 o;
  o.x = f2bf(v.x); o.y = f2bf(v.y); o.z = f2bf(v.z); o.w = f2bf(v.w);
  *(ushort4*)(out + idx) = o;
}

// ---------- causal row softmax on packed bf16 tiles, in place ----------
__global__ __launch_bounds__(256)
void softmax_packed(u16* __restrict__ sc)
{
  const int rowid = blockIdx.x;            // b*2048 + i
  const int b = rowid >> 11, i = rowid & 2047;
  const int mtt = i >> 7, rr = i & 127;
  u16* base = sc + (long)b * BATCH_SC + (long)(mtt * (mtt + 1) / 2) * 16384 + rr * 128;
  const int t = threadIdx.x;
  const int lane = t & 63, wv = t >> 6;
  const int L = i + 1, Lpad = (mtt + 1) << 7;
  float vals[8];
  float m = -1e30f;
#pragma unroll
  for (int u = 0; u < 8; ++u) {
    const int j = t + u * 256;
    if (j < L) { vals[u] = bf2f(base[(j >> 7) * 16384 + (j & 127)]); m = fmaxf(m, vals[u]); }
    else vals[u] = -1e30f;
  }
#pragma unroll
  for (int o = 1; o < 64; o <<= 1) m = fmaxf(m, __shfl_xor(m, o));
  __shared__ float rm[4], rsm[4];
  if (lane == 0) rm[wv] = m;
  __syncthreads();
  m = fmaxf(fmaxf(rm[0], rm[1]), fmaxf(rm[2], rm[3]));
  float pv[8];
  float ssum = 0.f;
#pragma unroll
  for (int u = 0; u < 8; ++u) { pv[u] = expf(vals[u] - m); ssum += pv[u]; }
#pragma unroll
  for (int o = 1; o < 64; o <<= 1) ssum += __shfl_xor(ssum, o);
  if (lane == 0) rsm[wv] = ssum;
  __syncthreads();   // all reads complete before writes
  ssum = rsm[0] + rsm[1] + rsm[2] + rsm[3];
  const float inv = 1.f / ssum;
#pragma unroll
  for (int u = 0; u < 8; ++u) {
    const int j = t + u * 256;
    if (j < Lpad) base[(j >> 7) * 16384 + (j & 127)] = f2bf(pv[u] * inv);
  }
}

// ---------- LayerNorm rows of 1024; OUTBF: 1 = bf16 out ----------
template<int OUTBF>
__global__ __launch_bounds__(256)
void layernorm_k(const float* __restrict__ in, const float* __restrict__ gam,
                 const float* __restrict__ bet, void* __restrict__ outv)
{
  const long row = blockIdx.x;
  const int t = threadIdx.x;
  const int lane = t & 63, wv = t >> 6;
  const float4 v = ((const float4*)(in + row * 1024))[t];
  float s = v.x + v.y + v.z + v.w;
  float q = v.x * v.x + v.y * v.y + v.z * v.z + v.w * v.w;
#pragma unroll
  for (int o = 1; o < 64; o <<= 1) { s += __shfl_xor(s, o); q += __shfl_xor(q, o); }
  __shared__ float rs[4], rq[4];
  if (lane == 0) { rs[wv] = s; rq[wv] = q; }
  __syncthreads();
  s = rs[0] + rs[1] + rs[2] + rs[3];
  q = rq[0] + rq[1] + rq[2] + rq[3];
  const float mean = s * (1.f / 1024.f);
  const float var  = q * (1.f / 1024.f) - mean * mean;
  const float rstd = rsqrtf(var + 1e-5f);
  const float4 g4 = ((const float4*)gam)[t];
  const float4 b4 = ((const float4*)bet)[t];
  const float o0 = (v.x - mean) * rstd * g4.x + b4.x;
  const float o1 = (v.y - mean) * rstd * g4.y + b4.y;
  const float o2 = (v.z - mean) * rstd * g4.z + b4.z;
  const float o3 = (v.w - mean) * rstd * g4.w + b4.w;
  if (OUTBF) {
    ushort4 o; o.x = f2bf(o0); o.y = f2bf(o1); o.z = f2bf(o2); o.w = f2bf(o3);
    ((ushort4*)outv)[row * 256 + t] = o;
  } else {
    ((float4*)outv)[row * 256 + t] = make_float4(o0, o1, o2, o3);
  }
}

// =====================================================================
extern "C" void kernel_launch(void* const* d_in, const int* in_sizes, int n_in,
                              void* d_out, int out_size, void* d_ws, size_t ws_size,
                              hipStream_t stream)
{
  const float* x   = (const float*)d_in[0];
  const float* Wq  = (const float*)d_in[1];
  const float* bq  = (const float*)d_in[2];
  const float* Wk  = (const float*)d_in[3];
  const float* bk  = (const float*)d_in[4];
  const float* Wv  = (const float*)d_in[5];
  const float* bv  = (const float*)d_in[6];
  const float* W1  = (const float*)d_in[7];
  const float* b1  = (const float*)d_in[8];
  const float* W2  = (const float*)d_in[9];
  const float* b2  = (const float*)d_in[10];
  const float* g1  = (const float*)d_in[11];
  const float* be1 = (const float*)d_in[12];
  const float* g2  = (const float*)d_in[13];
  const float* be2 = (const float*)d_in[14];

  // workspace (peak ~152 MiB), stream-ordered reuse:
  //  [0,32M)    xb (x bf16) -> vt (v^T) after QKV
  //  [32,64M)   q -> ln1 (after scores / after PV)
  //  [64,96M)   k -> h[0:32M) (FFN half-hidden, after scores)
  //  [96,128M)  v -> sc[0:32M) (after v-transpose) -> h[32:64M)
  //  [128,130M) sc tail (packed causal bf16 scores, 34 MiB total)
  //  [130..152M) bf16 [N][K] weights: Wqkv(6M) | W1T(8M) | W2T(8M)
  char* ws = (char*)d_ws;
  u16*   xb    = (u16*)(ws);
  u16*   vt    = xb;
  u16*   qkv   = (u16*)(ws + 33554432);          // q|k|v contiguous (16M elems each)
  u16*   qbuf  = qkv;
  u16*   kbuf  = qkv + 16777216;
  u16*   vbuf  = qkv + 33554432;
  u16*   ln1   = qbuf;                            // over q
  u16*   hbuf  = kbuf;                            // 64 MiB over k+v/sc
  u16*   sc    = (u16*)(ws + 100663296);          // packed scores over dead v
  u16*   wqkvT = (u16*)(ws + 136314880);
  u16*   w1T   = (u16*)(ws + 142606336);
  u16*   w2T   = (u16*)(ws + 150994944);
  float* attnf = (float*)d_out;                   // PV out f32 lives in d_out

  const dim3 B256(256);

  // 1. x -> bf16
  cvt_f32_to_bf16<<<dim3(16384), B256, 0, stream>>>(x, xb, 16777216L);

  // 2. weight transposes: f32 [K][N] -> bf16 [N][K]
  transpose_bf16<0><<<dim3(32, 32, 1),  B256, 0, stream>>>(Wq, wqkvT,           1024, 1024, 0, 0);
  transpose_bf16<0><<<dim3(32, 32, 1),  B256, 0, stream>>>(Wk, wqkvT + 1048576, 1024, 1024, 0, 0);
  transpose_bf16<0><<<dim3(32, 32, 1),  B256, 0, stream>>>(Wv, wqkvT + 2097152, 1024, 1024, 0, 0);
  transpose_bf16<0><<<dim3(128, 32, 1), B256, 0, stream>>>(W1, w1T, 1024, 4096, 0, 0);
  transpose_bf16<0><<<dim3(32, 128, 1), B256, 0, stream>>>(W2, w2T, 4096, 1024, 0, 0);

  // 3. fused QKV projection: M=16384, N=3072, K=1024 (grid 64x12)
  gemm256<0><<<dim3(768), dim3(512), 0, stream>>>(xb, 1024, wqkvT, 1024, qkv, 1024,
                                                  bq, bk, bv, nullptr, 1024, 64);

  // 4. v -> v^T per batch (2048x1024 -> 1024x2048), over dead xb
  transpose_bf16<1><<<dim3(32, 64, 8), B256, 0, stream>>>(vbuf, vt, 2048, 1024, 2097152, 2097152);

  // 5. scores = q@k^T/32 -> packed causal bf16 (all batches)
  gemm_bt<1><<<dim3(16, 16, 8), B256, 0, stream>>>(qbuf, 1024, 2097152, kbuf, 1024, 2097152,
                                                   sc, 0, 0, 1024, 0.03125f);

  // 6. row softmax in place on packed tiles
  softmax_packed<<<dim3(16384), B256, 0, stream>>>(sc);

  // 7. attn = probs @ v -> f32 directly into d_out (block-causal Keff)
  gemm_bt<2><<<dim3(8, 16, 8), B256, 0, stream>>>(sc, 0, 0, vt, 2048, 2097152,
                                                  attnf, 1024, 2097152, 0, 1.f);

  // 8. LN1: d_out f32 -> ln1 bf16
  layernorm_k<1><<<dim3(16384), B256, 0, stream>>>(attnf, g1, be1, ln1);

  // 9. FFN split along N_ff into 2 halves of 2048; f32 accumulation in d_out
  for (int j = 0; j < 2; ++j) {
    // h_j = gelu(ln1 @ W1[:, j*2048:+2048] + b1_j)  (M=16384,N=2048,K=1024; grid 64x8)
    gemm256<3><<<dim3(512), dim3(512), 0, stream>>>(ln1, 1024, w1T + (long)j * 2048 * 1024, 1024,
                                                    hbuf, 2048, b1 + j * 2048, nullptr, nullptr,
                                                    nullptr, 1024, 64);
    // d_out (+)= h_j @ W2[j*2048:+2048, :]  (M=16384,N=1024,K=2048; grid 64x4)
    if (j == 0)
      gemm256<4><<<dim3(256), dim3(512), 0, stream>>>(hbuf, 2048, w2T, 4096, d_out, 1024,
                                                      nullptr, nullptr, nullptr, nullptr, 2048, 64);
    else
      gemm256<5><<<dim3(256), dim3(512), 0, stream>>>(hbuf, 2048, w2T + 2048, 4096, d_out, 1024,
                                                      b2, nullptr, nullptr, ln1, 2048, 64);
  }

  // 10. LN2 in place on d_out (f32)
  layernorm_k<0><<<dim3(16384), B256, 0, stream>>>((float*)d_out, g2, be2, d_out);
}